// Round 7
// baseline (3264.046 us; speedup 1.0000x reference)
//
#include <hip/hip_runtime.h>

#define T_STEPS 128
#define BATCH   64
#define INDIM   512
#define HDIM    1024
#define NE      819
#define OUT0_SZ (T_STEPS*BATCH*HDIM)
#define BH      (BATCH*HDIM)          /* 65536 */
#define ALLH_L  (129*BH)

#define HS_LAY   131072               /* shorts per (parity,layer): 2 planes x 65536 */
#define HS_PAR   393216               /* shorts per parity (3 layers) */
#define XF_T     65536                /* shorts per timestep of x-frags: hi 32768 + lo 32768 */
#define NBLK     192

typedef short bf16x8 __attribute__((ext_vector_type(8)));
typedef short short2v __attribute__((ext_vector_type(2)));
typedef float f32x4  __attribute__((ext_vector_type(4)));
typedef float f32x2  __attribute__((ext_vector_type(2)));

__device__ __forceinline__ short f2bf(float f){
    unsigned u = __float_as_uint(f);
    u += 0x7FFF + ((u >> 16) & 1);           /* RNE */
    return (short)(u >> 16);
}
__device__ __forceinline__ float bf2f(short s){
    return __uint_as_float(((unsigned)(unsigned short)s) << 16);
}

/* ============ one-time prep: weights -> |.|*sign*emask, split hi/lo, frag-swizzled ============ */
/* layout per layer: [it(64)][kb(nkb)][hi(512)|lo(512)] shorts; L0 nkb=48, L1/2 nkb=64 */
__global__ __launch_bounds__(256) void ei_prep_w(const float* __restrict__ Win0,
        const float* __restrict__ Win1, const float* __restrict__ Win2,
        const float* __restrict__ Wrec, short* __restrict__ wf){
    int gid = blockIdx.x * 256 + threadIdx.x;      /* 0 .. 720895 */
    int j, local, nkb, kff; const float* Win; short* base;
    if (gid < 196608)      { j=0; local=gid;        nkb=48; kff=512;  Win=Win0; base=wf; }
    else if (gid < 458752) { j=1; local=gid-196608; nkb=64; kff=1024; Win=Win1; base=wf+3145728; }
    else                   { j=2; local=gid-458752; nkb=64; kff=1024; Win=Win2; base=wf+7340032; }
    int lane = local & 63;
    int fi   = local >> 6;                         /* it*nkb + kb */
    int kb   = fi % nkb;
    int it   = fi / nkb;
    int i    = it*16 + (lane & 15);
    int k0   = kb*32 + ((lane >> 4) << 3);
    const float* wrec_row = Wrec + ((size_t)j*HDIM + i)*HDIM;
    bf16x8 hv, lv;
    #pragma unroll
    for (int e = 0; e < 8; ++e){
        int k = k0 + e;
        float w;
        if (k < kff){
            w = fabsf(Win[(size_t)i*kff + k]);
            if (j != 0 && k >= NE) w = 0.f;        /* e_mask folded into ff weights */
        } else {
            int kr = k - kff;
            w = fabsf(wrec_row[kr]);
            if (kr >= NE) w = -w;                  /* Dale sign folded */
        }
        short h = f2bf(w);
        hv[e] = h;
        lv[e] = f2bf(w - bf2f(h));
    }
    short* dst = base + (size_t)fi*1024 + lane*8;
    *(bf16x8*)dst         = hv;
    *(bf16x8*)(dst + 512) = lv;
}

/* ============ one-time prep: x -> A-frag layout [t][plane][kb(16)][bt(4)][lane(64)][8] ============ */
__global__ __launch_bounds__(256) void ei_prep_xf(const float* __restrict__ x,
        short* __restrict__ xf){
    int gid = blockIdx.x * 256 + threadIdx.x;      /* 0 .. 524287 */
    int lane = gid & 63;
    int bt   = (gid >> 6) & 3;
    int kb   = (gid >> 8) & 15;
    int t    = gid >> 12;
    int b = bt*16 + (lane & 15);
    int k = kb*32 + ((lane >> 4) << 3);
    const float* src = x + ((size_t)t*BATCH + b)*INDIM + k;
    float4 v0 = *(const float4*)src;
    float4 v1 = *(const float4*)(src + 4);
    float f[8] = {v0.x,v0.y,v0.z,v0.w,v1.x,v1.y,v1.z,v1.w};
    bf16x8 hv, lv;
    #pragma unroll
    for (int e = 0; e < 8; ++e){
        short h = f2bf(f[e]);
        hv[e] = h; lv[e] = f2bf(f[e] - bf2f(h));
    }
    short* dst = xf + (size_t)t*XF_T + (((size_t)(kb*4 + bt)) << 9) + lane*8;
    *(bf16x8*)dst            = hv;
    *(bf16x8*)(dst + 32768)  = lv;
}

/* ============ init: all_h[l][0]=h0, h-frags (both parities), barrier state ============ */
__global__ __launch_bounds__(256) void ei_init4(const float* __restrict__ h0,
        float* __restrict__ out, short* __restrict__ hf, int* __restrict__ bar){
    int idx = blockIdx.x * 256 + threadIdx.x;      /* 0 .. 196607 */
    int l = idx >> 16, r = idx & 0xFFFF;
    out[OUT0_SZ + (size_t)l*ALLH_L + r] = h0[r];
    if (idx == 0){ bar[0] = 0; bar[1] = 0; }
    if (idx < 24576){
        int lane = idx & 63, bt = (idx >> 6) & 3, kb = (idx >> 8) & 31, j = idx >> 13;
        int b = bt*16 + (lane & 15);
        int k = kb*32 + ((lane >> 4) << 3);
        const float* src = h0 + (size_t)b*HDIM + k;
        float4 v0 = *(const float4*)src;
        float4 v1 = *(const float4*)(src + 4);
        float f[8] = {v0.x,v0.y,v0.z,v0.w,v1.x,v1.y,v1.z,v1.w};
        bf16x8 hv, lv;
        #pragma unroll
        for (int e = 0; e < 8; ++e){
            short hh = f2bf(f[e]);
            hv[e] = hh; lv[e] = f2bf(f[e] - bf2f(hh));
        }
        int off = ((kb*4 + bt) << 9) + lane*8;
        short* b0 = hf + (size_t)j*HS_LAY + off;
        *(bf16x8*)b0           = hv;
        *(bf16x8*)(b0 + 65536) = lv;
        short* b1 = b0 + HS_PAR;
        *(bf16x8*)b1           = hv;
        *(bf16x8*)(b1 + 65536) = lv;
    }
}

/* ============ per-step GEMM body: W from VGPRs, A streamed; 12 MFMA / kb ============ */
template<int NKW, int NKFF, int FFLO>
__device__ __forceinline__ void step_mm(
        const short* __restrict__ pff, const short* __restrict__ prec,
        const bf16x8 (&wbh)[8][2], const bf16x8 (&wbl)[8][2],
        int kb0, int btbase, int laneo, f32x4 acc[2][2])
{
    #pragma unroll
    for (int kk = 0; kk < NKW; ++kk){
        int kb = kb0 + kk;
        const short* pa; int lo;
        if (kb < NKFF){ pa = pff + (kb << 11); lo = FFLO; }
        else          { pa = prec + ((kb - NKFF) << 11); lo = 65536; }
        bf16x8 ah0 = *(const bf16x8*)(pa + ((btbase + 0) << 9) + laneo);
        bf16x8 ah1 = *(const bf16x8*)(pa + ((btbase + 1) << 9) + laneo);
        bf16x8 al0 = *(const bf16x8*)(pa + lo + ((btbase + 0) << 9) + laneo);
        bf16x8 al1 = *(const bf16x8*)(pa + lo + ((btbase + 1) << 9) + laneo);
        acc[0][0] = __builtin_amdgcn_mfma_f32_16x16x32_bf16(ah0, wbh[kk][0], acc[0][0], 0,0,0);
        acc[0][1] = __builtin_amdgcn_mfma_f32_16x16x32_bf16(ah1, wbh[kk][0], acc[0][1], 0,0,0);
        acc[1][0] = __builtin_amdgcn_mfma_f32_16x16x32_bf16(ah0, wbh[kk][1], acc[1][0], 0,0,0);
        acc[1][1] = __builtin_amdgcn_mfma_f32_16x16x32_bf16(ah1, wbh[kk][1], acc[1][1], 0,0,0);
        acc[0][0] = __builtin_amdgcn_mfma_f32_16x16x32_bf16(al0, wbh[kk][0], acc[0][0], 0,0,0);
        acc[0][1] = __builtin_amdgcn_mfma_f32_16x16x32_bf16(al1, wbh[kk][0], acc[0][1], 0,0,0);
        acc[1][0] = __builtin_amdgcn_mfma_f32_16x16x32_bf16(al0, wbh[kk][1], acc[1][0], 0,0,0);
        acc[1][1] = __builtin_amdgcn_mfma_f32_16x16x32_bf16(al1, wbh[kk][1], acc[1][1], 0,0,0);
        acc[0][0] = __builtin_amdgcn_mfma_f32_16x16x32_bf16(ah0, wbl[kk][0], acc[0][0], 0,0,0);
        acc[0][1] = __builtin_amdgcn_mfma_f32_16x16x32_bf16(ah1, wbl[kk][0], acc[0][1], 0,0,0);
        acc[1][0] = __builtin_amdgcn_mfma_f32_16x16x32_bf16(ah0, wbl[kk][1], acc[1][0], 0,0,0);
        acc[1][1] = __builtin_amdgcn_mfma_f32_16x16x32_bf16(ah1, wbl[kk][1], acc[1][1], 0,0,0);
    }
}

/* ============ persistent kernel: 192 blocks x 512 thr, W pinned in VGPRs,
   grid barrier per skewed step ============ */
__global__ __launch_bounds__(512, 2) void ei_persist(
        const short* __restrict__ xf, const short* __restrict__ wf,
        const float* __restrict__ bias, float* __restrict__ out,
        short* __restrict__ hf, int* __restrict__ bar)
{
    const int bid   = blockIdx.x;
    const int j     = bid >> 6;            /* 0..2 */
    const int rem   = bid & 63;
    const int strip = rem >> 1;            /* 0..31 : 32-col i-strip */
    const int bhalf = rem & 1;             /* batch half */
    const int tx    = threadIdx.x;
    const int wv    = tx >> 6, lane = tx & 63;
    const int laneo = lane * 8;
    const int btbase = bhalf * 2;          /* bt tiles {btbase, btbase+1} */
    const int it0   = strip * 2;

    const short* wfj = wf + (j == 0 ? 0 : (j == 1 ? 3145728 : 7340032));
    const int nkb  = (j == 0) ? 48 : 64;
    const int NKW  = nkb >> 3;             /* 6 or 8 */
    const int kb0  = wv * NKW;

    /* ---- one-time W load into VGPRs ---- */
    bf16x8 wbh[8][2], wbl[8][2];
    if (j == 0){
        #pragma unroll
        for (int kk = 0; kk < 6; ++kk)
            #pragma unroll
            for (int ic = 0; ic < 2; ++ic){
                const short* w0 = wfj + (it0 + ic)*48*1024 + (kb0 + kk)*1024 + laneo;
                wbh[kk][ic] = *(const bf16x8*)w0;
                wbl[kk][ic] = *(const bf16x8*)(w0 + 512);
            }
    } else {
        #pragma unroll
        for (int kk = 0; kk < 8; ++kk)
            #pragma unroll
            for (int ic = 0; ic < 2; ++ic){
                const short* w0 = wfj + (it0 + ic)*64*1024 + (kb0 + kk)*1024 + laneo;
                wbh[kk][ic] = *(const bf16x8*)w0;
                wbl[kk][ic] = *(const bf16x8*)(w0 + 512);
            }
    }

    /* ---- per-thread epilogue constants / state ---- */
    const int bl  = tx >> 4;               /* 0..31 local batch row */
    const int il0 = (tx & 15) << 1;        /* 0..30 local col pair */
    const int i_g = strip*32 + il0;
    const int b_g = bhalf*32 + bl;
    const f32x2 bb = *(const f32x2*)&bias[j*HDIM + i_g];
    f32x2 vreg = {0.f, 0.f};

    /* h-frag write offset for (b_g, i_g) */
    const int kb4 = i_g >> 5, btw = b_g >> 4;
    const int lnw = (b_g & 15) + (((i_g >> 3) & 3) << 4);
    const int hoff = ((kb4*4 + btw) << 9) + lnw*8 + (i_g & 7);

    __shared__ float psum[8][32][34];

    for (int s = 0; s < T_STEPS + 2; ++s){
        const int t = s - j;
        const bool act = (t >= 0) && (t < T_STEPS);
        if (act){
            const int par_r = (s - 1) & 1;
            const short* hfr  = hf + par_r*HS_PAR;
            const short* prec = hfr + j*HS_LAY;
            f32x4 acc[2][2] = {{{0.f,0.f,0.f,0.f},{0.f,0.f,0.f,0.f}},
                               {{0.f,0.f,0.f,0.f},{0.f,0.f,0.f,0.f}}};
            if (j == 0)
                step_mm<6,16,32768>(xf + t*XF_T, prec, wbh, wbl, kb0, btbase, laneo, acc);
            else if (j == 1)
                step_mm<8,32,65536>(hfr, prec, wbh, wbl, kb0, btbase, laneo, acc);
            else
                step_mm<8,32,65536>(hfr + HS_LAY, prec, wbh, wbl, kb0, btbase, laneo, acc);

            /* C/D layout: col=lane&15, row=(lane>>4)*4+r [m89] */
            const int r0 = (lane >> 4) << 2, l15 = lane & 15;
            #pragma unroll
            for (int ic = 0; ic < 2; ++ic)
                #pragma unroll
                for (int bt = 0; bt < 2; ++bt)
                    #pragma unroll
                    for (int r = 0; r < 4; ++r)
                        psum[wv][bt*16 + r0 + r][ic*16 + l15] = acc[ic][bt][r];
        }
        __syncthreads();
        if (act){
            float sum0 = 0.f, sum1 = 0.f;
            #pragma unroll
            for (int w = 0; w < 8; ++w){
                sum0 += psum[w][bl][il0];
                sum1 += psum[w][bl][il0 + 1];
            }
            vreg[0] = 0.8f*vreg[0] + 0.2f*(sum0 + bb[0]);
            vreg[1] = 0.8f*vreg[1] + 0.2f*(sum1 + bb[1]);
            float h0v = vreg[0] > 0.f ? vreg[0] : 0.f;
            float h1v = vreg[1] > 0.f ? vreg[1] : 0.f;
            f32x2 hv2 = {h0v, h1v};
            *(f32x2*)&out[OUT0_SZ + ((size_t)(j*129 + t + 1))*BH + b_g*HDIM + i_g] = hv2;
            const int par_w = s & 1;
            short* hww = hf + par_w*HS_PAR + j*HS_LAY;
            short hh0 = f2bf(h0v), hl0 = f2bf(h0v - bf2f(hh0));
            short hh1 = f2bf(h1v), hl1 = f2bf(h1v - bf2f(hh1));
            short2v hi2 = {hh0, hh1}, lo2 = {hl0, hl1};
            *(short2v*)(hww + hoff)         = hi2;
            *(short2v*)(hww + hoff + 65536) = lo2;
            if (j == 2){
                f32x2 o2 = {(i_g < NE) ? h0v : 0.f, (i_g + 1 < NE) ? h1v : 0.f};
                *(f32x2*)&out[(size_t)t*BH + b_g*HDIM + i_g] = o2;
            }
        }
        if (s == T_STEPS + 1) break;
        __syncthreads();
        /* ---- grid barrier: monotone counter + generation flag ---- */
        if (tx == 0){
            __threadfence();                               /* release: L2 writeback */
            int prev = __hip_atomic_fetch_add(&bar[0], 1,
                        __ATOMIC_ACQ_REL, __HIP_MEMORY_SCOPE_AGENT);
            if (prev == (s + 1)*NBLK - 1){
                __hip_atomic_store(&bar[1], s + 1,
                        __ATOMIC_RELEASE, __HIP_MEMORY_SCOPE_AGENT);
            } else {
                while (__hip_atomic_load(&bar[1],
                        __ATOMIC_RELAXED, __HIP_MEMORY_SCOPE_AGENT) < s + 1)
                    __builtin_amdgcn_s_sleep(2);
            }
            __threadfence();                               /* acquire: invalidate */
        }
        __syncthreads();
    }
}

/* ================= fp32 fallback path (kept for small ws_size) ================= */
__global__ __launch_bounds__(256) void ei_init(const float* __restrict__ h0,
                                               float* __restrict__ out,
                                               float* __restrict__ v_ws) {
    int idx = blockIdx.x * 256 + threadIdx.x;
    int l = idx >> 16, r = idx & 0xFFFF;
    out[OUT0_SZ + (size_t)l*ALLH_L + r] = h0[r];
    v_ws[idx] = 0.0f;
}

__global__ __launch_bounds__(256) void ei_stage(
    const float* __restrict__ xin, const float* __restrict__ Win0,
    const float* __restrict__ Win1, const float* __restrict__ Win2,
    const float* __restrict__ Wrec, const float* __restrict__ bias,
    float* __restrict__ out, float* __restrict__ v_ws, int s)
{
    const int j  = blockIdx.x >> 6;
    const int cb = blockIdx.x & 63;
    const int t  = s - j;
    if (t < 0 || t >= T_STEPS) return;
    float* all_h = out + OUT0_SZ;
    const float* Win = (j == 0) ? Win0 : (j == 1 ? Win1 : Win2);
    const int K1 = (j == 0) ? INDIM : HDIM;
    const float* Wr = Wrec + j * HDIM * HDIM;
    const float* ffp; int ffld;
    if (j == 0) { ffp = xin + (size_t)t * BATCH * INDIM; ffld = INDIM; }
    else        { ffp = all_h + ((size_t)(j - 1) * 129 + (t + 1)) * BH; ffld = HDIM; }
    const float* hj = all_h + ((size_t)j * 129 + t) * BH;
    __shared__ float Xs[64][68];
    __shared__ float Ws[16][65];
    const int tx = threadIdx.x;
    const int i_loc = tx & 15;
    const int b0 = (tx >> 4) * 4;
    const int i0 = cb * 16;
    float acc0 = 0.f, acc1 = 0.f, acc2 = 0.f, acc3 = 0.f;
    const int nch_ff = K1 >> 6;
    const int nch = nch_ff + (HDIM >> 6);
    for (int ch = 0; ch < nch; ++ch) {
        const bool ff = ch < nch_ff;
        const int kb = ff ? (ch << 6) : ((ch - nch_ff) << 6);
        __syncthreads();
        #pragma unroll
        for (int itr = 0; itr < 16; ++itr) {
            int idx = itr * 256 + tx;
            int bl2 = idx >> 6, kl = idx & 63, k = kb + kl;
            float v;
            if (ff) { v = ffp[bl2 * ffld + k]; if (j != 0 && k >= NE) v = 0.0f; }
            else    { v = hj[bl2 * HDIM + k];  if (k >= NE) v = -v; }
            Xs[kl][bl2] = v;
        }
        const float* W = ff ? Win : Wr;
        const int ldw = ff ? K1 : HDIM;
        #pragma unroll
        for (int itr = 0; itr < 4; ++itr) {
            int idx = itr * 256 + tx;
            int il = idx >> 6, kl = idx & 63;
            Ws[il][kl] = fabsf(W[(i0 + il) * ldw + kb + kl]);
        }
        __syncthreads();
        #pragma unroll
        for (int kk = 0; kk < 64; ++kk) {
            const float w = Ws[i_loc][kk];
            const float4 x4 = *reinterpret_cast<const float4*>(&Xs[kk][b0]);
            acc0 = fmaf(x4.x, w, acc0); acc1 = fmaf(x4.y, w, acc1);
            acc2 = fmaf(x4.z, w, acc2); acc3 = fmaf(x4.w, w, acc3);
        }
    }
    const int i = i0 + i_loc;
    const float bj = bias[j * HDIM + i];
    float accs[4] = {acc0, acc1, acc2, acc3};
    #pragma unroll
    for (int r = 0; r < 4; ++r) {
        const int b = b0 + r;
        const float pre = accs[r] + bj;
        float* vp = v_ws + ((size_t)j * BATCH + b) * HDIM + i;
        const float vn = 0.8f * (*vp) + 0.2f * pre;
        *vp = vn;
        const float h = vn > 0.f ? vn : 0.f;
        all_h[((size_t)j * 129 + (t + 1)) * BH + b * HDIM + i] = h;
        if (j == 2) out[((size_t)t * BATCH + b) * HDIM + i] = (i < NE) ? h : 0.f;
    }
}

extern "C" void kernel_launch(void* const* d_in, const int* in_sizes, int n_in,
                              void* d_out, int out_size, void* d_ws, size_t ws_size,
                              hipStream_t stream) {
    const float* xin  = (const float*)d_in[0];
    const float* h0   = (const float*)d_in[1];
    const float* Win0 = (const float*)d_in[2];
    const float* Win1 = (const float*)d_in[3];
    const float* Win2 = (const float*)d_in[4];
    const float* Wrec = (const float*)d_in[5];
    const float* bias = (const float*)d_in[6];
    float* out  = (float*)d_out;
    char* ws    = (char*)d_ws;

    /* layout: bar(256) | hf(1572864) | xf(16777216) | wf(23068672) */
    const size_t need = 256 + 1572864ULL + 16777216ULL + 23068672ULL; /* 41419008 */

    if (ws_size >= need) {
        int*   bar = (int*)ws;
        short* hf  = (short*)(ws + 256);
        short* xf  = (short*)(ws + 256 + 1572864ULL);
        short* wfp = (short*)(ws + 256 + 1572864ULL + 16777216ULL);
        hipLaunchKernelGGL(ei_prep_w, dim3(2816), dim3(256), 0, stream,
                           Win0, Win1, Win2, Wrec, wfp);
        hipLaunchKernelGGL(ei_prep_xf, dim3(2048), dim3(256), 0, stream, xin, xf);
        hipLaunchKernelGGL(ei_init4, dim3(768), dim3(256), 0, stream, h0, out, hf, bar);
        hipLaunchKernelGGL(ei_persist, dim3(NBLK), dim3(512), 0, stream,
                           xf, wfp, bias, out, hf, bar);
    } else {
        float* v_ws = (float*)ws;
        hipLaunchKernelGGL(ei_init, dim3(768), dim3(256), 0, stream, h0, out, v_ws);
        for (int s = 0; s < T_STEPS + 2; ++s)
            hipLaunchKernelGGL(ei_stage, dim3(192), dim3(256), 0, stream,
                               xin, Win0, Win1, Win2, Wrec, bias, out, v_ws, s);
    }
}

// Round 8
// 3089.929 us; speedup vs baseline: 1.0563x; 1.0563x over previous
//
#include <hip/hip_runtime.h>

#define T_STEPS 128
#define BATCH   64
#define INDIM   512
#define HDIM    1024
#define NE      819
#define OUT0_SZ (T_STEPS*BATCH*HDIM)
#define BH      (BATCH*HDIM)          /* 65536 */
#define ALLH_L  (129*BH)

#define HS_LAY   131072               /* shorts per (parity,layer): 2 planes x 65536 */
#define HS_PAR   393216               /* shorts per parity (3 layers) */
#define XF_T     65536                /* shorts per timestep of x-frags: hi 32768 + lo 32768 */
#define NBLK     192
#define NGRP     8                    /* barrier groups */
#define GSZ      24                   /* blocks per group */

typedef short bf16x8 __attribute__((ext_vector_type(8)));
typedef short short2v __attribute__((ext_vector_type(2)));
typedef float f32x4  __attribute__((ext_vector_type(4)));
typedef float f32x2  __attribute__((ext_vector_type(2)));

__device__ __forceinline__ short f2bf(float f){
    unsigned u = __float_as_uint(f);
    u += 0x7FFF + ((u >> 16) & 1);           /* RNE */
    return (short)(u >> 16);
}
__device__ __forceinline__ float bf2f(short s){
    return __uint_as_float(((unsigned)(unsigned short)s) << 16);
}

/* ============ one-time prep: weights -> |.|*sign*emask, split hi/lo, frag-swizzled ============ */
/* layout per layer: [it(64)][kb(nkb)][hi(512)|lo(512)] shorts; L0 nkb=48, L1/2 nkb=64 */
__global__ __launch_bounds__(256) void ei_prep_w(const float* __restrict__ Win0,
        const float* __restrict__ Win1, const float* __restrict__ Win2,
        const float* __restrict__ Wrec, short* __restrict__ wf){
    int gid = blockIdx.x * 256 + threadIdx.x;      /* 0 .. 720895 */
    int j, local, nkb, kff; const float* Win; short* base;
    if (gid < 196608)      { j=0; local=gid;        nkb=48; kff=512;  Win=Win0; base=wf; }
    else if (gid < 458752) { j=1; local=gid-196608; nkb=64; kff=1024; Win=Win1; base=wf+3145728; }
    else                   { j=2; local=gid-458752; nkb=64; kff=1024; Win=Win2; base=wf+7340032; }
    int lane = local & 63;
    int fi   = local >> 6;                         /* it*nkb + kb */
    int kb   = fi % nkb;
    int it   = fi / nkb;
    int i    = it*16 + (lane & 15);
    int k0   = kb*32 + ((lane >> 4) << 3);
    const float* wrec_row = Wrec + ((size_t)j*HDIM + i)*HDIM;
    bf16x8 hv, lv;
    #pragma unroll
    for (int e = 0; e < 8; ++e){
        int k = k0 + e;
        float w;
        if (k < kff){
            w = fabsf(Win[(size_t)i*kff + k]);
            if (j != 0 && k >= NE) w = 0.f;        /* e_mask folded into ff weights */
        } else {
            int kr = k - kff;
            w = fabsf(wrec_row[kr]);
            if (kr >= NE) w = -w;                  /* Dale sign folded */
        }
        short h = f2bf(w);
        hv[e] = h;
        lv[e] = f2bf(w - bf2f(h));
    }
    short* dst = base + (size_t)fi*1024 + lane*8;
    *(bf16x8*)dst         = hv;
    *(bf16x8*)(dst + 512) = lv;
}

/* ============ one-time prep: x -> A-frag layout [t][plane][kb(16)][bt(4)][lane(64)][8] ============ */
__global__ __launch_bounds__(256) void ei_prep_xf(const float* __restrict__ x,
        short* __restrict__ xf){
    int gid = blockIdx.x * 256 + threadIdx.x;      /* 0 .. 524287 */
    int lane = gid & 63;
    int bt   = (gid >> 6) & 3;
    int kb   = (gid >> 8) & 15;
    int t    = gid >> 12;
    int b = bt*16 + (lane & 15);
    int k = kb*32 + ((lane >> 4) << 3);
    const float* src = x + ((size_t)t*BATCH + b)*INDIM + k;
    float4 v0 = *(const float4*)src;
    float4 v1 = *(const float4*)(src + 4);
    float f[8] = {v0.x,v0.y,v0.z,v0.w,v1.x,v1.y,v1.z,v1.w};
    bf16x8 hv, lv;
    #pragma unroll
    for (int e = 0; e < 8; ++e){
        short h = f2bf(f[e]);
        hv[e] = h; lv[e] = f2bf(f[e] - bf2f(h));
    }
    short* dst = xf + (size_t)t*XF_T + (((size_t)(kb*4 + bt)) << 9) + lane*8;
    *(bf16x8*)dst            = hv;
    *(bf16x8*)(dst + 32768)  = lv;
}

/* ============ init: all_h[l][0]=h0, h-frags (both parities), barrier state ============ */
__global__ __launch_bounds__(256) void ei_init4(const float* __restrict__ h0,
        float* __restrict__ out, short* __restrict__ hf, int* __restrict__ bar){
    int idx = blockIdx.x * 256 + threadIdx.x;      /* 0 .. 196607 */
    int l = idx >> 16, r = idx & 0xFFFF;
    out[OUT0_SZ + (size_t)l*ALLH_L + r] = h0[r];
    if (idx < 1024) bar[idx] = 0;                  /* counters + flags, all lines */
    if (idx < 24576){
        int lane = idx & 63, bt = (idx >> 6) & 3, kb = (idx >> 8) & 31, j = idx >> 13;
        int b = bt*16 + (lane & 15);
        int k = kb*32 + ((lane >> 4) << 3);
        const float* src = h0 + (size_t)b*HDIM + k;
        float4 v0 = *(const float4*)src;
        float4 v1 = *(const float4*)(src + 4);
        float f[8] = {v0.x,v0.y,v0.z,v0.w,v1.x,v1.y,v1.z,v1.w};
        bf16x8 hv, lv;
        #pragma unroll
        for (int e = 0; e < 8; ++e){
            short hh = f2bf(f[e]);
            hv[e] = hh; lv[e] = f2bf(f[e] - bf2f(hh));
        }
        int off = ((kb*4 + bt) << 9) + lane*8;
        short* b0 = hf + (size_t)j*HS_LAY + off;
        *(bf16x8*)b0           = hv;
        *(bf16x8*)(b0 + 65536) = lv;
        short* b1 = b0 + HS_PAR;
        *(bf16x8*)b1           = hv;
        *(bf16x8*)(b1 + 65536) = lv;
    }
}

/* ============ per-step GEMM body: depth-2 double-buffered W AND A, 12 MFMA / kb ============ */
template<int NKW, int NKFF, int FFLO>
__device__ __forceinline__ void step_mm2(
        const short* __restrict__ pff, const short* __restrict__ prec,
        const short* __restrict__ wp0, const short* __restrict__ wp1,
        int kb0, int btbase, int laneo, f32x4 acc[2][2])
{
    bf16x8 wh[2][2], wl[2][2], ah[2][2], al[2][2];
    auto loadW = [&](int kk, int buf){
        const short* a = wp0 + ((kb0 + kk) << 10);
        const short* b = wp1 + ((kb0 + kk) << 10);
        wh[buf][0] = *(const bf16x8*)a; wl[buf][0] = *(const bf16x8*)(a + 512);
        wh[buf][1] = *(const bf16x8*)b; wl[buf][1] = *(const bf16x8*)(b + 512);
    };
    auto loadA = [&](int kk, int buf){
        int kb = kb0 + kk;
        const short* pa; int lo;
        if (kb < NKFF){ pa = pff + (kb << 11); lo = FFLO; }
        else          { pa = prec + ((kb - NKFF) << 11); lo = 65536; }
        ah[buf][0] = *(const bf16x8*)(pa + ((btbase + 0) << 9) + laneo);
        ah[buf][1] = *(const bf16x8*)(pa + ((btbase + 1) << 9) + laneo);
        al[buf][0] = *(const bf16x8*)(pa + lo + ((btbase + 0) << 9) + laneo);
        al[buf][1] = *(const bf16x8*)(pa + lo + ((btbase + 1) << 9) + laneo);
    };
    loadW(0, 0); loadA(0, 0);
    #pragma unroll
    for (int kk = 0; kk < NKW; ++kk){
        if (kk + 1 < NKW){ loadW(kk + 1, (kk + 1) & 1); loadA(kk + 1, (kk + 1) & 1); }
        const int b = kk & 1;
        acc[0][0] = __builtin_amdgcn_mfma_f32_16x16x32_bf16(ah[b][0], wh[b][0], acc[0][0], 0,0,0);
        acc[0][1] = __builtin_amdgcn_mfma_f32_16x16x32_bf16(ah[b][1], wh[b][0], acc[0][1], 0,0,0);
        acc[1][0] = __builtin_amdgcn_mfma_f32_16x16x32_bf16(ah[b][0], wh[b][1], acc[1][0], 0,0,0);
        acc[1][1] = __builtin_amdgcn_mfma_f32_16x16x32_bf16(ah[b][1], wh[b][1], acc[1][1], 0,0,0);
        acc[0][0] = __builtin_amdgcn_mfma_f32_16x16x32_bf16(al[b][0], wh[b][0], acc[0][0], 0,0,0);
        acc[0][1] = __builtin_amdgcn_mfma_f32_16x16x32_bf16(al[b][1], wh[b][0], acc[0][1], 0,0,0);
        acc[1][0] = __builtin_amdgcn_mfma_f32_16x16x32_bf16(al[b][0], wh[b][1], acc[1][0], 0,0,0);
        acc[1][1] = __builtin_amdgcn_mfma_f32_16x16x32_bf16(al[b][1], wh[b][1], acc[1][1], 0,0,0);
        acc[0][0] = __builtin_amdgcn_mfma_f32_16x16x32_bf16(ah[b][0], wl[b][0], acc[0][0], 0,0,0);
        acc[0][1] = __builtin_amdgcn_mfma_f32_16x16x32_bf16(ah[b][1], wl[b][0], acc[0][1], 0,0,0);
        acc[1][0] = __builtin_amdgcn_mfma_f32_16x16x32_bf16(ah[b][0], wl[b][1], acc[1][0], 0,0,0);
        acc[1][1] = __builtin_amdgcn_mfma_f32_16x16x32_bf16(ah[b][1], wl[b][1], acc[1][1], 0,0,0);
    }
}

/* ============ persistent kernel v2: two-level barrier, replicated poll flags ============ */
/* bar layout (ints): cnt[g] @ g*32 (g=0..7) | super @ 256 | flag[g] @ 512+g*32 */
__global__ __launch_bounds__(512, 2) void ei_persist2(
        const short* __restrict__ xf, const short* __restrict__ wf,
        const float* __restrict__ bias, float* __restrict__ out,
        short* __restrict__ hf, int* __restrict__ bar)
{
    const int bid   = blockIdx.x;
    const int j     = bid >> 6;            /* 0..2 */
    const int rem   = bid & 63;
    const int strip = rem >> 1;            /* 0..31 : 32-col i-strip */
    const int bhalf = rem & 1;             /* batch half */
    const int tx    = threadIdx.x;
    const int wv    = tx >> 6, lane = tx & 63;
    const int laneo = lane * 8;
    const int btbase = bhalf * 2;          /* bt tiles {btbase, btbase+1} */
    const int it0   = strip * 2;
    const int grp   = bid & (NGRP - 1);

    const short* wfj = wf + (j == 0 ? 0 : (j == 1 ? 3145728 : 7340032));
    const int nkb  = (j == 0) ? 48 : 64;
    const int NKW  = nkb >> 3;             /* 6 or 8 */
    const int kb0  = wv * NKW;
    const short* wp0 = wfj + it0*nkb*1024 + laneo;
    const short* wp1 = wp0 + nkb*1024;

    /* ---- per-thread epilogue constants / state ---- */
    const int bl  = tx >> 4;               /* 0..31 local batch row */
    const int il0 = (tx & 15) << 1;        /* 0..30 local col pair */
    const int i_g = strip*32 + il0;
    const int b_g = bhalf*32 + bl;
    const f32x2 bb = *(const f32x2*)&bias[j*HDIM + i_g];
    f32x2 vreg = {0.f, 0.f};

    /* h-frag write offset for (b_g, i_g) */
    const int kb4 = i_g >> 5, btw = b_g >> 4;
    const int lnw = (b_g & 15) + (((i_g >> 3) & 3) << 4);
    const int hoff = ((kb4*4 + btw) << 9) + lnw*8 + (i_g & 7);

    __shared__ float psum[8][32][34];

    for (int s = 0; s < T_STEPS + 2; ++s){
        const int t = s - j;
        const bool act = (t >= 0) && (t < T_STEPS);
        if (act){
            const int par_r = (s - 1) & 1;
            const short* hfr  = hf + par_r*HS_PAR;
            const short* prec = hfr + j*HS_LAY;
            f32x4 acc[2][2] = {{{0.f,0.f,0.f,0.f},{0.f,0.f,0.f,0.f}},
                               {{0.f,0.f,0.f,0.f},{0.f,0.f,0.f,0.f}}};
            if (j == 0)
                step_mm2<6,16,32768>(xf + t*XF_T, prec, wp0, wp1, kb0, btbase, laneo, acc);
            else if (j == 1)
                step_mm2<8,32,65536>(hfr, prec, wp0, wp1, kb0, btbase, laneo, acc);
            else
                step_mm2<8,32,65536>(hfr + HS_LAY, prec, wp0, wp1, kb0, btbase, laneo, acc);

            /* C/D layout: col=lane&15, row=(lane>>4)*4+r [m89] */
            const int r0 = (lane >> 4) << 2, l15 = lane & 15;
            #pragma unroll
            for (int ic = 0; ic < 2; ++ic)
                #pragma unroll
                for (int bt = 0; bt < 2; ++bt)
                    #pragma unroll
                    for (int r = 0; r < 4; ++r)
                        psum[wv][bt*16 + r0 + r][ic*16 + l15] = acc[ic][bt][r];
        }
        __syncthreads();
        if (act){
            float sum0 = 0.f, sum1 = 0.f;
            #pragma unroll
            for (int w = 0; w < 8; ++w){
                f32x2 p = *(f32x2*)&psum[w][bl][il0];
                sum0 += p[0]; sum1 += p[1];
            }
            vreg[0] = 0.8f*vreg[0] + 0.2f*(sum0 + bb[0]);
            vreg[1] = 0.8f*vreg[1] + 0.2f*(sum1 + bb[1]);
            float h0v = vreg[0] > 0.f ? vreg[0] : 0.f;
            float h1v = vreg[1] > 0.f ? vreg[1] : 0.f;
            f32x2 hv2 = {h0v, h1v};
            *(f32x2*)&out[OUT0_SZ + ((size_t)(j*129 + t + 1))*BH + b_g*HDIM + i_g] = hv2;
            const int par_w = s & 1;
            short* hww = hf + par_w*HS_PAR + j*HS_LAY;
            short hh0 = f2bf(h0v), hl0 = f2bf(h0v - bf2f(hh0));
            short hh1 = f2bf(h1v), hl1 = f2bf(h1v - bf2f(hh1));
            short2v hi2 = {hh0, hh1}, lo2 = {hl0, hl1};
            *(short2v*)(hww + hoff)         = hi2;
            *(short2v*)(hww + hoff + 65536) = lo2;
            if (j == 2){
                f32x2 o2 = {(i_g < NE) ? h0v : 0.f, (i_g + 1 < NE) ? h1v : 0.f};
                *(f32x2*)&out[(size_t)t*BH + b_g*HDIM + i_g] = o2;
            }
        }
        if (s == T_STEPS + 1) break;
        __syncthreads();
        /* ---- two-level grid barrier: 8 group counters -> super -> 8 flag replicas ---- */
        if (tx == 0){
            __threadfence();                               /* release block's stores */
            int prev = __hip_atomic_fetch_add(&bar[grp*32], 1,
                        __ATOMIC_ACQ_REL, __HIP_MEMORY_SCOPE_AGENT);
            if (prev == (s + 1)*GSZ - 1){
                int sp = __hip_atomic_fetch_add(&bar[256], 1,
                        __ATOMIC_ACQ_REL, __HIP_MEMORY_SCOPE_AGENT);
                if (sp == (s + 1)*NGRP - 1){
                    #pragma unroll
                    for (int g = 0; g < NGRP; ++g)
                        __hip_atomic_store(&bar[512 + g*32], s + 1,
                                __ATOMIC_RELEASE, __HIP_MEMORY_SCOPE_AGENT);
                }
            }
            while (__hip_atomic_load(&bar[512 + grp*32],
                    __ATOMIC_RELAXED, __HIP_MEMORY_SCOPE_AGENT) < s + 1)
                __builtin_amdgcn_s_sleep(8);
            __threadfence();                               /* acquire */
        }
        __syncthreads();
    }
}

/* ================= fp32 fallback path (kept for small ws_size) ================= */
__global__ __launch_bounds__(256) void ei_init(const float* __restrict__ h0,
                                               float* __restrict__ out,
                                               float* __restrict__ v_ws) {
    int idx = blockIdx.x * 256 + threadIdx.x;
    int l = idx >> 16, r = idx & 0xFFFF;
    out[OUT0_SZ + (size_t)l*ALLH_L + r] = h0[r];
    v_ws[idx] = 0.0f;
}

__global__ __launch_bounds__(256) void ei_stage(
    const float* __restrict__ xin, const float* __restrict__ Win0,
    const float* __restrict__ Win1, const float* __restrict__ Win2,
    const float* __restrict__ Wrec, const float* __restrict__ bias,
    float* __restrict__ out, float* __restrict__ v_ws, int s)
{
    const int j  = blockIdx.x >> 6;
    const int cb = blockIdx.x & 63;
    const int t  = s - j;
    if (t < 0 || t >= T_STEPS) return;
    float* all_h = out + OUT0_SZ;
    const float* Win = (j == 0) ? Win0 : (j == 1 ? Win1 : Win2);
    const int K1 = (j == 0) ? INDIM : HDIM;
    const float* Wr = Wrec + j * HDIM * HDIM;
    const float* ffp; int ffld;
    if (j == 0) { ffp = xin + (size_t)t * BATCH * INDIM; ffld = INDIM; }
    else        { ffp = all_h + ((size_t)(j - 1) * 129 + (t + 1)) * BH; ffld = HDIM; }
    const float* hj = all_h + ((size_t)j * 129 + t) * BH;
    __shared__ float Xs[64][68];
    __shared__ float Ws[16][65];
    const int tx = threadIdx.x;
    const int i_loc = tx & 15;
    const int b0 = (tx >> 4) * 4;
    const int i0 = cb * 16;
    float acc0 = 0.f, acc1 = 0.f, acc2 = 0.f, acc3 = 0.f;
    const int nch_ff = K1 >> 6;
    const int nch = nch_ff + (HDIM >> 6);
    for (int ch = 0; ch < nch; ++ch) {
        const bool ff = ch < nch_ff;
        const int kb = ff ? (ch << 6) : ((ch - nch_ff) << 6);
        __syncthreads();
        #pragma unroll
        for (int itr = 0; itr < 16; ++itr) {
            int idx = itr * 256 + tx;
            int bl2 = idx >> 6, kl = idx & 63, k = kb + kl;
            float v;
            if (ff) { v = ffp[bl2 * ffld + k]; if (j != 0 && k >= NE) v = 0.0f; }
            else    { v = hj[bl2 * HDIM + k];  if (k >= NE) v = -v; }
            Xs[kl][bl2] = v;
        }
        const float* W = ff ? Win : Wr;
        const int ldw = ff ? K1 : HDIM;
        #pragma unroll
        for (int itr = 0; itr < 4; ++itr) {
            int idx = itr * 256 + tx;
            int il = idx >> 6, kl = idx & 63;
            Ws[il][kl] = fabsf(W[(i0 + il) * ldw + kb + kl]);
        }
        __syncthreads();
        #pragma unroll
        for (int kk = 0; kk < 64; ++kk) {
            const float w = Ws[i_loc][kk];
            const float4 x4 = *reinterpret_cast<const float4*>(&Xs[kk][b0]);
            acc0 = fmaf(x4.x, w, acc0); acc1 = fmaf(x4.y, w, acc1);
            acc2 = fmaf(x4.z, w, acc2); acc3 = fmaf(x4.w, w, acc3);
        }
    }
    const int i = i0 + i_loc;
    const float bj = bias[j * HDIM + i];
    float accs[4] = {acc0, acc1, acc2, acc3};
    #pragma unroll
    for (int r = 0; r < 4; ++r) {
        const int b = b0 + r;
        const float pre = accs[r] + bj;
        float* vp = v_ws + ((size_t)j * BATCH + b) * HDIM + i;
        const float vn = 0.8f * (*vp) + 0.2f * pre;
        *vp = vn;
        const float h = vn > 0.f ? vn : 0.f;
        all_h[((size_t)j * 129 + (t + 1)) * BH + b * HDIM + i] = h;
        if (j == 2) out[((size_t)t * BATCH + b) * HDIM + i] = (i < NE) ? h : 0.f;
    }
}

extern "C" void kernel_launch(void* const* d_in, const int* in_sizes, int n_in,
                              void* d_out, int out_size, void* d_ws, size_t ws_size,
                              hipStream_t stream) {
    const float* xin  = (const float*)d_in[0];
    const float* h0   = (const float*)d_in[1];
    const float* Win0 = (const float*)d_in[2];
    const float* Win1 = (const float*)d_in[3];
    const float* Win2 = (const float*)d_in[4];
    const float* Wrec = (const float*)d_in[5];
    const float* bias = (const float*)d_in[6];
    float* out  = (float*)d_out;
    char* ws    = (char*)d_ws;

    /* layout: bar(4096) | hf(1572864) | xf(16777216) | wf(23068672) */
    const size_t need = 4096 + 1572864ULL + 16777216ULL + 23068672ULL; /* 41422848 */

    if (ws_size >= need) {
        int*   bar = (int*)ws;
        short* hf  = (short*)(ws + 4096);
        short* xf  = (short*)(ws + 4096 + 1572864ULL);
        short* wfp = (short*)(ws + 4096 + 1572864ULL + 16777216ULL);
        hipLaunchKernelGGL(ei_prep_w, dim3(2816), dim3(256), 0, stream,
                           Win0, Win1, Win2, Wrec, wfp);
        hipLaunchKernelGGL(ei_prep_xf, dim3(2048), dim3(256), 0, stream, xin, xf);
        hipLaunchKernelGGL(ei_init4, dim3(768), dim3(256), 0, stream, h0, out, hf, bar);
        hipLaunchKernelGGL(ei_persist2, dim3(NBLK), dim3(512), 0, stream,
                           xf, wfp, bias, out, hf, bar);
    } else {
        float* v_ws = (float*)ws;
        hipLaunchKernelGGL(ei_init, dim3(768), dim3(256), 0, stream, h0, out, v_ws);
        for (int s = 0; s < T_STEPS + 2; ++s)
            hipLaunchKernelGGL(ei_stage, dim3(192), dim3(256), 0, stream,
                               xin, Win0, Win1, Win2, Wrec, bias, out, v_ws, s);
    }
}

// Round 9
// 1079.435 us; speedup vs baseline: 3.0238x; 2.8625x over previous
//
#include <hip/hip_runtime.h>

#define T_STEPS 128
#define BATCH   64
#define INDIM   512
#define HDIM    1024
#define NE      819
#define OUT0_SZ (T_STEPS*BATCH*HDIM)
#define BH      (BATCH*HDIM)          /* 65536 */
#define ALLH_L  (129*BH)

#define HS_LAY   131072               /* shorts per (slot,layer): hi 65536 + lo 65536 */
#define HS_SLOT  393216               /* shorts per slot (3 layers) */
#define NSLOT    131                  /* full-depth h ring: writes at s -> slot s+1 */
#define XF_T     65536                /* shorts per timestep of x-frags: hi 32768 + lo 32768 */
#define NBLK     192
#define NGRP     8                    /* barrier groups == presumed XCDs */
#define GSZ      24                   /* blocks per group */

typedef short bf16x8 __attribute__((ext_vector_type(8)));
typedef short short2v __attribute__((ext_vector_type(2)));
typedef float f32x4  __attribute__((ext_vector_type(4)));
typedef float f32x2  __attribute__((ext_vector_type(2)));

__device__ __forceinline__ short f2bf(float f){
    unsigned u = __float_as_uint(f);
    u += 0x7FFF + ((u >> 16) & 1);           /* RNE */
    return (short)(u >> 16);
}
__device__ __forceinline__ float bf2f(short s){
    return __uint_as_float(((unsigned)(unsigned short)s) << 16);
}

/* ============ one-time prep: weights -> |.|*sign*emask, split hi/lo, frag-swizzled ============ */
__global__ __launch_bounds__(256) void ei_prep_w(const float* __restrict__ Win0,
        const float* __restrict__ Win1, const float* __restrict__ Win2,
        const float* __restrict__ Wrec, short* __restrict__ wf){
    int gid = blockIdx.x * 256 + threadIdx.x;      /* 0 .. 720895 */
    int j, local, nkb, kff; const float* Win; short* base;
    if (gid < 196608)      { j=0; local=gid;        nkb=48; kff=512;  Win=Win0; base=wf; }
    else if (gid < 458752) { j=1; local=gid-196608; nkb=64; kff=1024; Win=Win1; base=wf+3145728; }
    else                   { j=2; local=gid-458752; nkb=64; kff=1024; Win=Win2; base=wf+7340032; }
    int lane = local & 63;
    int fi   = local >> 6;
    int kb   = fi % nkb;
    int it   = fi / nkb;
    int i    = it*16 + (lane & 15);
    int k0   = kb*32 + ((lane >> 4) << 3);
    const float* wrec_row = Wrec + ((size_t)j*HDIM + i)*HDIM;
    bf16x8 hv, lv;
    #pragma unroll
    for (int e = 0; e < 8; ++e){
        int k = k0 + e;
        float w;
        if (k < kff){
            w = fabsf(Win[(size_t)i*kff + k]);
            if (j != 0 && k >= NE) w = 0.f;
        } else {
            int kr = k - kff;
            w = fabsf(wrec_row[kr]);
            if (kr >= NE) w = -w;
        }
        short h = f2bf(w);
        hv[e] = h;
        lv[e] = f2bf(w - bf2f(h));
    }
    short* dst = base + (size_t)fi*1024 + lane*8;
    *(bf16x8*)dst         = hv;
    *(bf16x8*)(dst + 512) = lv;
}

/* ============ one-time prep: x -> A-frag layout [t][plane][kb(16)][bt(4)][lane(64)][8] ============ */
__global__ __launch_bounds__(256) void ei_prep_xf(const float* __restrict__ x,
        short* __restrict__ xf){
    int gid = blockIdx.x * 256 + threadIdx.x;      /* 0 .. 524287 */
    int lane = gid & 63;
    int bt   = (gid >> 6) & 3;
    int kb   = (gid >> 8) & 15;
    int t    = gid >> 12;
    int b = bt*16 + (lane & 15);
    int k = kb*32 + ((lane >> 4) << 3);
    const float* src = x + ((size_t)t*BATCH + b)*INDIM + k;
    float4 v0 = *(const float4*)src;
    float4 v1 = *(const float4*)(src + 4);
    float f[8] = {v0.x,v0.y,v0.z,v0.w,v1.x,v1.y,v1.z,v1.w};
    bf16x8 hv, lv;
    #pragma unroll
    for (int e = 0; e < 8; ++e){
        short h = f2bf(f[e]);
        hv[e] = h; lv[e] = f2bf(f[e] - bf2f(h));
    }
    short* dst = xf + (size_t)t*XF_T + (((size_t)(kb*4 + bt)) << 9) + lane*8;
    *(bf16x8*)dst            = hv;
    *(bf16x8*)(dst + 32768)  = lv;
}

/* ============ init for persistent path: all_h[l][0]=h0, h-frag slot 0, barrier zero ===== */
__global__ __launch_bounds__(256) void ei_init5(const float* __restrict__ h0,
        float* __restrict__ out, short* __restrict__ hf, int* __restrict__ bar){
    int idx = blockIdx.x * 256 + threadIdx.x;      /* 0 .. 196607 */
    int l = idx >> 16, r = idx & 0xFFFF;
    out[OUT0_SZ + (size_t)l*ALLH_L + r] = h0[r];
    if (idx < 1024) bar[idx] = 0;
    if (idx < 24576){
        int lane = idx & 63, bt = (idx >> 6) & 3, kb = (idx >> 8) & 31, j = idx >> 13;
        int b = bt*16 + (lane & 15);
        int k = kb*32 + ((lane >> 4) << 3);
        const float* src = h0 + (size_t)b*HDIM + k;
        float4 v0 = *(const float4*)src;
        float4 v1 = *(const float4*)(src + 4);
        float f[8] = {v0.x,v0.y,v0.z,v0.w,v1.x,v1.y,v1.z,v1.w};
        bf16x8 hv, lv;
        #pragma unroll
        for (int e = 0; e < 8; ++e){
            short hh = f2bf(f[e]);
            hv[e] = hh; lv[e] = f2bf(f[e] - bf2f(hh));
        }
        int off = ((kb*4 + bt) << 9) + lane*8;
        short* b0 = hf + (size_t)j*HS_LAY + off;   /* slot 0 */
        *(bf16x8*)b0           = hv;
        *(bf16x8*)(b0 + 65536) = lv;
    }
}

/* ============ per-step GEMM body: depth-2 double-buffered W AND A ============ */
template<int NKW, int NKFF, int FFLO>
__device__ __forceinline__ void step_mm2(
        const short* __restrict__ pff, const short* __restrict__ prec,
        const short* __restrict__ wp0, const short* __restrict__ wp1,
        int kb0, int btbase, int laneo, f32x4 acc[2][2])
{
    bf16x8 wh[2][2], wl[2][2], ah[2][2], al[2][2];
    auto loadW = [&](int kk, int buf){
        const short* a = wp0 + ((kb0 + kk) << 10);
        const short* b = wp1 + ((kb0 + kk) << 10);
        wh[buf][0] = *(const bf16x8*)a; wl[buf][0] = *(const bf16x8*)(a + 512);
        wh[buf][1] = *(const bf16x8*)b; wl[buf][1] = *(const bf16x8*)(b + 512);
    };
    auto loadA = [&](int kk, int buf){
        int kb = kb0 + kk;
        const short* pa; int lo;
        if (kb < NKFF){ pa = pff + (kb << 11); lo = FFLO; }
        else          { pa = prec + ((kb - NKFF) << 11); lo = 65536; }
        ah[buf][0] = *(const bf16x8*)(pa + ((btbase + 0) << 9) + laneo);
        ah[buf][1] = *(const bf16x8*)(pa + ((btbase + 1) << 9) + laneo);
        al[buf][0] = *(const bf16x8*)(pa + lo + ((btbase + 0) << 9) + laneo);
        al[buf][1] = *(const bf16x8*)(pa + lo + ((btbase + 1) << 9) + laneo);
    };
    loadW(0, 0); loadA(0, 0);
    #pragma unroll
    for (int kk = 0; kk < NKW; ++kk){
        if (kk + 1 < NKW){ loadW(kk + 1, (kk + 1) & 1); loadA(kk + 1, (kk + 1) & 1); }
        const int b = kk & 1;
        acc[0][0] = __builtin_amdgcn_mfma_f32_16x16x32_bf16(ah[b][0], wh[b][0], acc[0][0], 0,0,0);
        acc[0][1] = __builtin_amdgcn_mfma_f32_16x16x32_bf16(ah[b][1], wh[b][0], acc[0][1], 0,0,0);
        acc[1][0] = __builtin_amdgcn_mfma_f32_16x16x32_bf16(ah[b][0], wh[b][1], acc[1][0], 0,0,0);
        acc[1][1] = __builtin_amdgcn_mfma_f32_16x16x32_bf16(ah[b][1], wh[b][1], acc[1][1], 0,0,0);
        acc[0][0] = __builtin_amdgcn_mfma_f32_16x16x32_bf16(al[b][0], wh[b][0], acc[0][0], 0,0,0);
        acc[0][1] = __builtin_amdgcn_mfma_f32_16x16x32_bf16(al[b][1], wh[b][0], acc[0][1], 0,0,0);
        acc[1][0] = __builtin_amdgcn_mfma_f32_16x16x32_bf16(al[b][0], wh[b][1], acc[1][0], 0,0,0);
        acc[1][1] = __builtin_amdgcn_mfma_f32_16x16x32_bf16(al[b][1], wh[b][1], acc[1][1], 0,0,0);
        acc[0][0] = __builtin_amdgcn_mfma_f32_16x16x32_bf16(ah[b][0], wl[b][0], acc[0][0], 0,0,0);
        acc[0][1] = __builtin_amdgcn_mfma_f32_16x16x32_bf16(ah[b][1], wl[b][0], acc[0][1], 0,0,0);
        acc[1][0] = __builtin_amdgcn_mfma_f32_16x16x32_bf16(ah[b][0], wl[b][1], acc[1][0], 0,0,0);
        acc[1][1] = __builtin_amdgcn_mfma_f32_16x16x32_bf16(ah[b][1], wl[b][1], acc[1][1], 0,0,0);
    }
}

/* ============ persistent v3: NO fences. Full-depth hf ring (virgin addresses each step),
   sc0sc1 write-through h stores, relaxed two-level barrier, XCD-aware work mapping. ===== */
__global__ __launch_bounds__(512, 2) void ei_persist3(
        const short* __restrict__ xf, const short* __restrict__ wf,
        const float* __restrict__ bias, float* __restrict__ out,
        short* __restrict__ hf, int* __restrict__ bar)
{
    const int bid   = blockIdx.x;
    /* XCD-aware mapping: presumed XCD g = bid&7 owns strips 4g..4g+3 for all layers.
       Per-XCD W footprint = 2.75 MB < 4 MiB L2 -> W stays L2-resident (no fences ever). */
    const int g     = bid & 7;
    const int w     = bid >> 3;            /* 0..23 */
    const int j     = w >> 3;              /* 0..2 */
    const int strip = g*4 + ((w >> 1) & 3);/* 0..31 */
    const int bhalf = w & 1;
    const int grp   = g;

    const int tx    = threadIdx.x;
    const int wv    = tx >> 6, lane = tx & 63;
    const int laneo = lane * 8;
    const int btbase = bhalf * 2;
    const int it0   = strip * 2;

    const short* wfj = wf + (j == 0 ? 0 : (j == 1 ? 3145728 : 7340032));
    const int nkb  = (j == 0) ? 48 : 64;
    const int NKW  = nkb >> 3;
    const int kb0  = wv * NKW;
    const short* wp0 = wfj + it0*nkb*1024 + laneo;
    const short* wp1 = wp0 + nkb*1024;

    const int bl  = tx >> 4;
    const int il0 = (tx & 15) << 1;
    const int i_g = strip*32 + il0;
    const int b_g = bhalf*32 + bl;
    const f32x2 bb = *(const f32x2*)&bias[j*HDIM + i_g];
    f32x2 vreg = {0.f, 0.f};

    const int kb4 = i_g >> 5, btw = b_g >> 4;
    const int lnw = (b_g & 15) + (((i_g >> 3) & 3) << 4);
    const int hoff = ((kb4*4 + btw) << 9) + lnw*8 + (i_g & 7);

    __shared__ float psum[8][32][34];

    for (int s = 0; s < T_STEPS + 2; ++s){
        const int t = s - j;
        const bool act = (t >= 0) && (t < T_STEPS);
        if (act){
            const short* hfr  = hf + (size_t)s*HS_SLOT;          /* slot s = written at s-1 */
            const short* prec = (t == 0) ? (hf + (size_t)j*HS_LAY)        /* init slot 0 */
                                         : (hfr + (size_t)j*HS_LAY);
            f32x4 acc[2][2] = {{{0.f,0.f,0.f,0.f},{0.f,0.f,0.f,0.f}},
                               {{0.f,0.f,0.f,0.f},{0.f,0.f,0.f,0.f}}};
            if (j == 0)
                step_mm2<6,16,32768>(xf + (size_t)t*XF_T, prec, wp0, wp1, kb0, btbase, laneo, acc);
            else if (j == 1)
                step_mm2<8,32,65536>(hfr, prec, wp0, wp1, kb0, btbase, laneo, acc);
            else
                step_mm2<8,32,65536>(hfr + HS_LAY, prec, wp0, wp1, kb0, btbase, laneo, acc);

            /* C/D layout: col=lane&15, row=(lane>>4)*4+r [m89] */
            const int r0 = (lane >> 4) << 2, l15 = lane & 15;
            #pragma unroll
            for (int ic = 0; ic < 2; ++ic)
                #pragma unroll
                for (int bt = 0; bt < 2; ++bt)
                    #pragma unroll
                    for (int r = 0; r < 4; ++r)
                        psum[wv][bt*16 + r0 + r][ic*16 + l15] = acc[ic][bt][r];
        }
        __syncthreads();
        if (act){
            float sum0 = 0.f, sum1 = 0.f;
            #pragma unroll
            for (int ww = 0; ww < 8; ++ww){
                f32x2 p = *(f32x2*)&psum[ww][bl][il0];
                sum0 += p[0]; sum1 += p[1];
            }
            vreg[0] = 0.8f*vreg[0] + 0.2f*(sum0 + bb[0]);
            vreg[1] = 0.8f*vreg[1] + 0.2f*(sum1 + bb[1]);
            float h0v = vreg[0] > 0.f ? vreg[0] : 0.f;
            float h1v = vreg[1] > 0.f ? vreg[1] : 0.f;
            f32x2 hv2 = {h0v, h1v};
            *(f32x2*)&out[OUT0_SZ + ((size_t)(j*129 + t + 1))*BH + b_g*HDIM + i_g] = hv2;
            /* h-frags: write-through to coherence point (sc0 sc1), virgin slot s+1 */
            short hh0 = f2bf(h0v), hl0 = f2bf(h0v - bf2f(hh0));
            short hh1 = f2bf(h1v), hl1 = f2bf(h1v - bf2f(hh1));
            int hi2 = (int)(unsigned short)hh0 | ((int)(unsigned short)hh1 << 16);
            int lo2 = (int)(unsigned short)hl0 | ((int)(unsigned short)hl1 << 16);
            short* hww = hf + (size_t)(s + 1)*HS_SLOT + (size_t)j*HS_LAY + hoff;
            asm volatile("global_store_dword %0, %1, off sc0 sc1"
                         :: "v"(hww), "v"(hi2) : "memory");
            asm volatile("global_store_dword %0, %1, off sc0 sc1"
                         :: "v"(hww + 65536), "v"(lo2) : "memory");
            if (j == 2){
                f32x2 o2 = {(i_g < NE) ? h0v : 0.f, (i_g + 1 < NE) ? h1v : 0.f};
                *(f32x2*)&out[(size_t)t*BH + b_g*HDIM + i_g] = o2;
            }
        }
        if (s == T_STEPS + 1) break;
        /* every thread drains its own stores (sc1 -> visible at coherence point) */
        asm volatile("s_waitcnt vmcnt(0)" ::: "memory");
        __syncthreads();
        /* ---- relaxed two-level grid barrier (NO buffer_wbl2 / buffer_inv) ---- */
        if (tx == 0){
            int prev = __hip_atomic_fetch_add(&bar[grp*32], 1,
                        __ATOMIC_RELAXED, __HIP_MEMORY_SCOPE_AGENT);
            if (prev == (s + 1)*GSZ - 1){
                int sp = __hip_atomic_fetch_add(&bar[256], 1,
                        __ATOMIC_RELAXED, __HIP_MEMORY_SCOPE_AGENT);
                if (sp == (s + 1)*NGRP - 1){
                    #pragma unroll
                    for (int gg = 0; gg < NGRP; ++gg)
                        __hip_atomic_store(&bar[512 + gg*32], s + 1,
                                __ATOMIC_RELAXED, __HIP_MEMORY_SCOPE_AGENT);
                }
            }
            while (__hip_atomic_load(&bar[512 + grp*32],
                    __ATOMIC_RELAXED, __HIP_MEMORY_SCOPE_AGENT) < s + 1)
                __builtin_amdgcn_s_sleep(2);
        }
        __syncthreads();
    }
}

/* ================= fallback tier: r6 multi-launch (proven 1550 us) ================= */
#define HS_PAR_FB 393216
__global__ __launch_bounds__(256) void ei_init3(const float* __restrict__ h0,
        float* __restrict__ out, float* __restrict__ v_ws, short* __restrict__ hfb){
    int idx = blockIdx.x * 256 + threadIdx.x;
    int l = idx >> 16, r = idx & 0xFFFF;
    float h = h0[r];
    out[OUT0_SZ + (size_t)l*ALLH_L + r] = h;
    v_ws[idx] = 0.f;
    if (idx < 24576){
        int lane = idx & 63, bt = (idx >> 6) & 3, kb = (idx >> 8) & 31, j = idx >> 13;
        int b = bt*16 + (lane & 15);
        int k = kb*32 + ((lane >> 4) << 3);
        const float* src = h0 + (size_t)b*HDIM + k;
        float4 v0 = *(const float4*)src;
        float4 v1 = *(const float4*)(src + 4);
        float f[8] = {v0.x,v0.y,v0.z,v0.w,v1.x,v1.y,v1.z,v1.w};
        bf16x8 hv, lv;
        #pragma unroll
        for (int e = 0; e < 8; ++e){
            short hh = f2bf(f[e]);
            hv[e] = hh; lv[e] = f2bf(f[e] - bf2f(hh));
        }
        int off = ((kb*4 + bt) << 9) + lane*8;
        short* b0 = hfb + (size_t)j*HS_LAY + off;
        *(bf16x8*)b0           = hv;
        *(bf16x8*)(b0 + 65536) = lv;
        short* b1 = b0 + HS_PAR_FB;
        *(bf16x8*)b1           = hv;
        *(bf16x8*)(b1 + 65536) = lv;
    }
}

template<int NKW, int NKFF, int FFLO>
__device__ __forceinline__ void stage_body5(
        const short* __restrict__ pff, const short* __restrict__ prec,
        const short* __restrict__ wp, int kb0, int laneo, f32x4 acc[4])
{
    bf16x8 wbh[NKW], wbl[NKW];
    #pragma unroll
    for (int kk = 0; kk < NKW; ++kk){
        const short* w0 = wp + ((kb0 + kk) << 10);
        wbh[kk] = *(const bf16x8*)w0;
        wbl[kk] = *(const bf16x8*)(w0 + 512);
    }
    bf16x8 ah[2][4], al[2][4];
    auto loadA = [&](int kk, int buf){
        int kb = kb0 + kk;
        const short* pa; int lo;
        if (kb < NKFF){ pa = pff + (kb << 11); lo = FFLO; }
        else          { pa = prec + ((kb - NKFF) << 11); lo = 65536; }
        #pragma unroll
        for (int bt = 0; bt < 4; ++bt){
            ah[buf][bt] = *(const bf16x8*)(pa + (bt << 9) + laneo);
            al[buf][bt] = *(const bf16x8*)(pa + lo + (bt << 9) + laneo);
        }
    };
    loadA(0, 0);
    #pragma unroll
    for (int kk = 0; kk < NKW; ++kk){
        if (kk + 1 < NKW) loadA(kk + 1, (kk + 1) & 1);
        const int bf = kk & 1;
        #pragma unroll
        for (int bt = 0; bt < 4; ++bt)
            acc[bt] = __builtin_amdgcn_mfma_f32_16x16x32_bf16(ah[bf][bt], wbh[kk], acc[bt], 0,0,0);
        #pragma unroll
        for (int bt = 0; bt < 4; ++bt)
            acc[bt] = __builtin_amdgcn_mfma_f32_16x16x32_bf16(al[bf][bt], wbh[kk], acc[bt], 0,0,0);
        #pragma unroll
        for (int bt = 0; bt < 4; ++bt)
            acc[bt] = __builtin_amdgcn_mfma_f32_16x16x32_bf16(ah[bf][bt], wbl[kk], acc[bt], 0,0,0);
    }
}

__global__ __launch_bounds__(512, 2) void ei_stage5(
        const short* __restrict__ xf, const short* __restrict__ wf,
        const float* __restrict__ bias, float* __restrict__ out,
        float* __restrict__ v_ws, short* __restrict__ hfb, int s)
{
    int j = blockIdx.x >> 6;
    int t = s - j;
    if (t < 0 || t >= T_STEPS) return;
    int it = blockIdx.x & 63;
    int wv = threadIdx.x >> 6, lane = threadIdx.x & 63;
    int laneo = lane * 8;
    int par_r = (s - 1) & 1, par_w = s & 1;
    const short* hfr  = hfb + par_r*HS_PAR_FB;
    const short* prec = hfr + j*HS_LAY;

    f32x4 acc[4] = {{0.f,0.f,0.f,0.f},{0.f,0.f,0.f,0.f},
                    {0.f,0.f,0.f,0.f},{0.f,0.f,0.f,0.f}};

    if (j == 0){
        const short* pff = xf + t*XF_T;
        const short* wp  = wf + it*48*1024 + laneo;
        stage_body5<6,16,32768>(pff, prec, wp, wv*6, laneo, acc);
    } else if (j == 1){
        const short* pff = hfr;
        const short* wp  = wf + 3145728 + it*64*1024 + laneo;
        stage_body5<8,32,65536>(pff, prec, wp, wv*8, laneo, acc);
    } else {
        const short* pff = hfr + HS_LAY;
        const short* wp  = wf + 7340032 + it*64*1024 + laneo;
        stage_body5<8,32,65536>(pff, prec, wp, wv*8, laneo, acc);
    }

    __shared__ float psum[8][64][18];
    {
        int r0 = (lane >> 4) << 2, l15 = lane & 15;
        #pragma unroll
        for (int bt = 0; bt < 4; ++bt)
            #pragma unroll
            for (int r = 0; r < 4; ++r)
                psum[wv][bt*16 + r0 + r][l15] = acc[bt][r];
    }
    __syncthreads();

    int tx  = threadIdx.x;
    int b   = tx >> 3;
    int il0 = (tx & 7) << 1;
    float* allh = out + OUT0_SZ + ((size_t)(j*129 + t + 1))*BH;
    float* outp = out + (size_t)t*BH;
    short* hww  = hfb + par_w*HS_PAR_FB + j*HS_LAY;
    float sum0 = 0.f, sum1 = 0.f;
    #pragma unroll
    for (int w = 0; w < 8; ++w){
        f32x2 p = *(f32x2*)&psum[w][b][il0];
        sum0 += p[0]; sum1 += p[1];
    }
    int i = it*16 + il0;
    f32x2 bb = *(const f32x2*)&bias[j*HDIM + i];
    int vo = (j*BATCH + b)*HDIM + i;
    f32x2 vold = *(f32x2*)&v_ws[vo];
    float vn0 = 0.8f * vold[0] + 0.2f * (sum0 + bb[0]);
    float vn1 = 0.8f * vold[1] + 0.2f * (sum1 + bb[1]);
    f32x2 vnv = {vn0, vn1};
    *(f32x2*)&v_ws[vo] = vnv;
    float h0 = vn0 > 0.f ? vn0 : 0.f;
    float h1 = vn1 > 0.f ? vn1 : 0.f;
    f32x2 hv2 = {h0, h1};
    *(f32x2*)&allh[b*HDIM + i] = hv2;
    short hh0 = f2bf(h0), hl0 = f2bf(h0 - bf2f(hh0));
    short hh1 = f2bf(h1), hl1 = f2bf(h1 - bf2f(hh1));
    int kb  = i >> 5, btw = b >> 4;
    int lnw = (b & 15) + (((i >> 3) & 3) << 4);
    int off = ((kb*4 + btw) << 9) + lnw*8 + (i & 7);
    short2v hi2 = {hh0, hh1}, lo2 = {hl0, hl1};
    *(short2v*)(hww + off)         = hi2;
    *(short2v*)(hww + off + 65536) = lo2;
    if (j == 2){
        f32x2 o2 = {(i < NE) ? h0 : 0.f, (i + 1 < NE) ? h1 : 0.f};
        *(f32x2*)&outp[b*HDIM + i] = o2;
    }
}

extern "C" void kernel_launch(void* const* d_in, const int* in_sizes, int n_in,
                              void* d_out, int out_size, void* d_ws, size_t ws_size,
                              hipStream_t stream) {
    const float* xin  = (const float*)d_in[0];
    const float* h0   = (const float*)d_in[1];
    const float* Win0 = (const float*)d_in[2];
    const float* Win1 = (const float*)d_in[3];
    const float* Win2 = (const float*)d_in[4];
    const float* Wrec = (const float*)d_in[5];
    const float* bias = (const float*)d_in[6];
    float* out  = (float*)d_out;
    char* ws    = (char*)d_ws;

    /* persistent layout: bar(4096) | hf(131*786432) | xf(16777216) | wf(23068672) */
    const size_t HF_B   = (size_t)NSLOT * HS_SLOT * 2ULL;            /* 103,022,592 */
    const size_t need_p = 4096 + HF_B + 16777216ULL + 23068672ULL;   /* 142,872,576 */
    /* fallback layout: v(786432) | hf2(1572864) | xf | wf = 42,205,184 (proven) */
    const size_t need_f = 786432ULL + 1572864ULL + 16777216ULL + 23068672ULL;

    if (ws_size >= need_p) {
        int*   bar = (int*)ws;
        short* hf  = (short*)(ws + 4096);
        short* xf  = (short*)(ws + 4096 + HF_B);
        short* wfp = (short*)(ws + 4096 + HF_B + 16777216ULL);
        hipLaunchKernelGGL(ei_prep_w, dim3(2816), dim3(256), 0, stream,
                           Win0, Win1, Win2, Wrec, wfp);
        hipLaunchKernelGGL(ei_prep_xf, dim3(2048), dim3(256), 0, stream, xin, xf);
        hipLaunchKernelGGL(ei_init5, dim3(768), dim3(256), 0, stream, h0, out, hf, bar);
        hipLaunchKernelGGL(ei_persist3, dim3(NBLK), dim3(512), 0, stream,
                           xf, wfp, bias, out, hf, bar);
    } else {
        float* v_ws = (float*)ws;
        short* hfb  = (short*)(ws + 786432);
        short* xf   = (short*)(ws + 786432 + 1572864ULL);
        short* wfp  = (short*)(ws + 786432 + 1572864ULL + 16777216ULL);
        hipLaunchKernelGGL(ei_prep_w, dim3(2816), dim3(256), 0, stream,
                           Win0, Win1, Win2, Wrec, wfp);
        hipLaunchKernelGGL(ei_prep_xf, dim3(2048), dim3(256), 0, stream, xin, xf);
        hipLaunchKernelGGL(ei_init3, dim3(768), dim3(256), 0, stream, h0, out, v_ws, hfb);
        for (int s = 0; s < T_STEPS + 2; ++s)
            hipLaunchKernelGGL(ei_stage5, dim3(192), dim3(512), 0, stream,
                               xf, wfp, bias, out, v_ws, hfb, s);
    }
}